// Round 4
// baseline (934.685 us; speedup 1.0000x reference)
//
#include <hip/hip_runtime.h>
#include <hip/hip_bf16.h>
#include <stdint.h>

#define NROWS 500000
#define INC 256
#define OUTC 112

typedef __attribute__((ext_vector_type(8))) short short8;
typedef __attribute__((ext_vector_type(4))) float f32x4;

static __device__ __forceinline__ uint32_t as_u32(float f) {
    union { float f; uint32_t u; } v; v.f = f; return v.u;
}
static __device__ __forceinline__ float as_f32(uint32_t u) {
    union { float f; uint32_t u; } v; v.u = u; return v.f;
}
// round-to-nearest-even bf16 (upper 16 bits); carry into exponent is correct.
static __device__ __forceinline__ unsigned short bf16_rne(float f) {
    uint32_t u = as_u32(f);
    uint32_t r = u + 0x7FFFu + ((u >> 16) & 1u);
    return (unsigned short)(r >> 16);
}
static __device__ __forceinline__ float bf16_to_f32(unsigned short h) {
    return as_f32(((uint32_t)h) << 16);
}

// ---------------- Prepass 1: convert W0 (scaled by wcat[:,0]) to bf16 hi/lo
// fragments (RNE), and build sorted relu-threshold array + ranks. ----------
// Fragment layout: Wh[(k>>3)][col][k&7] so a lane's 8 consecutive k-values
// (k = kt*32 + (lane>>4)*8 + j) for col = ct*16 + (lane&15) are one 16B load.
__global__ __launch_bounds__(256) void prep1(
    const float* __restrict__ W0, const float* __restrict__ Wn,
    const float* __restrict__ bn, const float* __restrict__ wcat,
    unsigned short* __restrict__ Wh, unsigned short* __restrict__ Wl,
    float* __restrict__ sortedTheta, int* __restrict__ rankArr)
{
    int tid = threadIdx.x;
    int gtid = blockIdx.x * 256 + tid;
    for (int idx = gtid; idx < OUTC * INC; idx += 8 * 256) {
        int col = idx >> 8;     // W0 is [112][256] row-major
        int k   = idx & 255;
        float w = W0[idx] * wcat[col * 2 + 0];   // fold wcat[:,0] into W0
        unsigned short hi = bf16_rne(w);
        float resid = w - bf16_to_f32(hi);       // exact in fp32
        unsigned short lo = bf16_rne(resid);
        int dst = (k >> 3) * (OUTC * 8) + col * 8 + (k & 7);
        Wh[dst] = hi;
        Wl[dst] = lo;
    }
    if (blockIdx.x == 0) {
        // relu(t*Wn[j]+bn[j]) crosses zero at theta_j = -bn/Wn (Wn!=0).
        __shared__ float sth[128];
        float th = INFINITY;
        if (tid < 112) {
            float w = Wn[tid];
            th = (w != 0.0f) ? (-bn[tid] / w) : INFINITY;
        }
        if (tid < 128) sth[tid] = th;
        __syncthreads();
        if (tid < 128) {
            int rank = 0;
            for (int i = 0; i < 128; ++i) {
                float o = sth[i];
                rank += (o < th) || (o == th && i < tid);  // stable rank, unique
            }
            sortedTheta[rank] = th;   // 128 entries; pads sort to the top as +inf
            rankArr[tid] = rank;
        }
    }
}

// ---------------- Prepass 2: per-segment linear tables ----------------
// For t in segment s (s = #{theta < t}):  z[k] = A[s][k]*t + C-part
// active(j): Wn>0 -> rank_j < s ; Wn<0 -> rank_j >= s ; Wn==0 -> bn>0
// Folds wcat[:,1], bc, bcat and wcat[:,0]*b0 into the C table.
__global__ __launch_bounds__(128) void prep2(
    const float* __restrict__ Wn, const float* __restrict__ bn,
    const float* __restrict__ Wc, const float* __restrict__ bc,
    const float* __restrict__ wcat, const float* __restrict__ bcat,
    const float* __restrict__ b0, const int* __restrict__ rankArr,
    float* __restrict__ Atab, float* __restrict__ Ctab)
{
    int s = blockIdx.x;      // 0..112
    int k = threadIdx.x;     // 0..127
    __shared__ float sw[112], sb[112];
    __shared__ int sr[112];
    if (k < 112) { sw[k] = Wn[k]; sb[k] = bn[k]; sr[k] = rankArr[k]; }
    __syncthreads();
    if (k >= OUTC) return;
    float a = 0.f, c = 0.f;
    const float* wcrow = Wc + k * OUTC;   // Wc is [112][112] row-major
    for (int j = 0; j < OUTC; ++j) {
        float w = sw[j];
        bool act = (w == 0.0f) ? (sb[j] > 0.0f)
                               : ((w > 0.0f) ? (sr[j] < s) : (sr[j] >= s));
        if (act) { float wc = wcrow[j]; a += wc * w; c += wc * sb[j]; }
    }
    float w1 = wcat[k * 2 + 1];
    Atab[s * OUTC + k] = w1 * a;
    Ctab[s * OUTC + k] = w1 * (c + bc[k]) + bcat[k] + wcat[k * 2 + 0] * b0[k];
}

// ---------------- Main kernel ----------------
// Each wave: 32 rows x 112 cols, K=256 in 8 k-tiles of mfma_f32_16x16x32_bf16,
// 3 products per tile (hh, hl, lh). Operands SWAPPED vs the naive mapping:
// mfma(Wfrag, xfrag) so D row = W-col, D col = x-row -> each lane holds 4
// CONSECUTIVE out columns of one row -> float4 epilogue stores/table loads.
// x loads are plain cached loads (NT hints caused HBM over-fetch risk on
// 16B-per-lane requests sharing 64B lines). W fragments stream from L2.
__global__ __launch_bounds__(256) void NodePredictor_main(
    const float* __restrict__ x, const float* __restrict__ node_info,
    const unsigned short* __restrict__ Wh, const unsigned short* __restrict__ Wl,
    const float* __restrict__ sortedTheta,
    const float* __restrict__ Atab, const float* __restrict__ Ctab,
    float* __restrict__ out)
{
    __shared__ float sTh[128];
    int tid = threadIdx.x;
    if (tid < 128) sTh[tid] = sortedTheta[tid];
    __syncthreads();

    int lane = tid & 63;
    int wv = tid >> 6;
    long tile = (long)blockIdx.x * 4 + wv;
    long base = tile * 32;
    if (base >= NROWS) return;     // 500000 = 32*15625 exactly; guard tail waves
    int l15 = lane & 15;
    int kg  = lane >> 4;

    // --- per-lane rows: r0 = base + l15, r1 = base + 16 + l15 ---
    float t0 = node_info[base + l15];
    float t1 = node_info[base + 16 + l15];
    int s0 = 0, s1 = 0;
    #pragma unroll
    for (int st = 64; st > 0; st >>= 1) {
        if (sTh[s0 + st - 1] < t0) s0 += st;   // #{theta < t}; pads are +inf
        if (sTh[s1 + st - 1] < t1) s1 += st;
    }

    f32x4 acc[2][7];
    #pragma unroll
    for (int rt = 0; rt < 2; ++rt)
        #pragma unroll
        for (int ct = 0; ct < 7; ++ct)
            acc[rt][ct] = (f32x4){0.f, 0.f, 0.f, 0.f};

    #pragma unroll 2
    for (int kt = 0; kt < 8; ++kt) {
        int g = kt * 4 + kg;
        // x fragments: row = lane&15 (+rt*16), k = kt*32 + (lane>>4)*8 + j
        short8 ah[2], al[2];
        #pragma unroll
        for (int rt = 0; rt < 2; ++rt) {
            const float* xp = x + (base + rt * 16 + l15) * (long)INC + kt * 32 + kg * 8;
            f32x4 v0 = *(const f32x4*)xp;
            f32x4 v1 = *(const f32x4*)(xp + 4);
            #pragma unroll
            for (int j = 0; j < 8; ++j) {
                float f = (j < 4) ? v0[j] : v1[j - 4];
                unsigned short hi = bf16_rne(f);
                float resid = f - bf16_to_f32(hi);   // exact
                ah[rt][j] = (short)hi;
                al[rt][j] = (short)bf16_rne(resid);
            }
        }
        // W fragments from L2: col = ct*16 + (lane&15), same k-group g
        const short8* Bh = (const short8*)(Wh + (size_t)g * OUTC * 8);
        const short8* Bl = (const short8*)(Wl + (size_t)g * OUTC * 8);
        #pragma unroll
        for (int ct = 0; ct < 7; ++ct) {
            short8 bh = Bh[ct * 16 + l15];
            short8 bl = Bl[ct * 16 + l15];
            #pragma unroll
            for (int rt = 0; rt < 2; ++rt) {
                // D = W^T-block * x-block: row = W-col, col = x-row
                acc[rt][ct] = __builtin_amdgcn_mfma_f32_16x16x32_bf16(bh, ah[rt], acc[rt][ct], 0, 0, 0);
                acc[rt][ct] = __builtin_amdgcn_mfma_f32_16x16x32_bf16(bl, ah[rt], acc[rt][ct], 0, 0, 0);
                acc[rt][ct] = __builtin_amdgcn_mfma_f32_16x16x32_bf16(bh, al[rt], acc[rt][ct], 0, 0, 0);
            }
        }
    }

    // --- epilogue: out[row][col..col+3] = acc + A[seg]*t + C[seg], float4 ---
    #pragma unroll
    for (int rt = 0; rt < 2; ++rt) {
        float t = rt ? t1 : t0;
        int seg = rt ? s1 : s0;
        long row = base + rt * 16 + l15;
        const float* Ar = Atab + seg * OUTC;
        const float* Cr = Ctab + seg * OUTC;
        float* orow = out + row * (long)OUTC;
        #pragma unroll
        for (int ct = 0; ct < 7; ++ct) {
            int col = ct * 16 + kg * 4;
            f32x4 Av = *(const f32x4*)(Ar + col);
            f32x4 Cv = *(const f32x4*)(Cr + col);
            f32x4 v = acc[rt][ct];
            f32x4 o;
            #pragma unroll
            for (int i = 0; i < 4; ++i) o[i] = v[i] + Av[i] * t + Cv[i];
            __builtin_nontemporal_store(o, (f32x4*)(orow + col));
        }
    }
}

extern "C" void kernel_launch(void* const* d_in, const int* in_sizes, int n_in,
                              void* d_out, int out_size, void* d_ws, size_t ws_size,
                              hipStream_t stream)
{
    const float* x    = (const float*)d_in[0];
    const float* ni   = (const float*)d_in[1];
    const float* W0   = (const float*)d_in[2];
    const float* b0   = (const float*)d_in[3];
    const float* Wn   = (const float*)d_in[4];
    const float* bn   = (const float*)d_in[5];
    const float* Wc   = (const float*)d_in[6];
    const float* bc   = (const float*)d_in[7];
    const float* wcat = (const float*)d_in[8];
    const float* bcat = (const float*)d_in[9];
    float* out = (float*)d_out;

    char* ws = (char*)d_ws;
    unsigned short* Wh   = (unsigned short*)(ws);              // 57344 B
    unsigned short* Wl   = (unsigned short*)(ws + 57344);      // 57344 B
    float* sTheta        = (float*)(ws + 114688);              // 512 B
    int* rankArr         = (int*)(ws + 115200);                // 512 B
    float* Atab          = (float*)(ws + 115712);              // 50624 B
    float* Ctab          = (float*)(ws + 166336);              // 50624 B -> 216960 total

    prep1<<<8, 256, 0, stream>>>(W0, Wn, bn, wcat, Wh, Wl, sTheta, rankArr);
    prep2<<<113, 128, 0, stream>>>(Wn, bn, Wc, bc, wcat, bcat, b0, rankArr, Atab, Ctab);

    const int tiles = (NROWS + 31) / 32;          // 15625
    const int blocks = (tiles + 3) / 4;           // 3907, 4 waves/block
    NodePredictor_main<<<blocks, 256, 0, stream>>>(x, ni, Wh, Wl, sTheta, Atab, Ctab, out);
}

// Round 9
// 789.749 us; speedup vs baseline: 1.1835x; 1.1835x over previous
//
#include <hip/hip_runtime.h>
#include <hip/hip_bf16.h>
#include <stdint.h>

#define NROWS 500000
#define INC 256
#define OUTC 112

typedef __attribute__((ext_vector_type(8))) short short8;
typedef __attribute__((ext_vector_type(4))) float f32x4;

static __device__ __forceinline__ uint32_t as_u32(float f) {
    union { float f; uint32_t u; } v; v.f = f; return v.u;
}
static __device__ __forceinline__ float as_f32(uint32_t u) {
    union { float f; uint32_t u; } v; v.u = u; return v.f;
}
// round-to-nearest-even bf16 (upper 16 bits); carry into exponent is correct.
static __device__ __forceinline__ unsigned short bf16_rne(float f) {
    uint32_t u = as_u32(f);
    uint32_t r = u + 0x7FFFu + ((u >> 16) & 1u);
    return (unsigned short)(r >> 16);
}
static __device__ __forceinline__ float bf16_to_f32(unsigned short h) {
    return as_f32(((uint32_t)h) << 16);
}

// convert 8 fp32 (two f32x4) -> bf16 hi + residual-lo fragments
static __device__ __forceinline__ void conv8(const f32x4& a, const f32x4& b,
                                             short8& hi, short8& lo) {
    #pragma unroll
    for (int j = 0; j < 8; ++j) {
        float f = (j < 4) ? a[j] : b[j - 4];
        unsigned short h = bf16_rne(f);
        hi[j] = (short)h;
        lo[j] = (short)bf16_rne(f - bf16_to_f32(h));
    }
}

// ---------------- Prepass 1: W0*wcat0 -> bf16 hi/lo fragment layout + sorted
// relu thresholds. Fragment layout: W[(k>>3)][col][k&7] (g-major, contiguous
// Wh then Wl so the main kernel stages both with one linear copy). ----------
__global__ __launch_bounds__(256) void prep1(
    const float* __restrict__ W0, const float* __restrict__ Wn,
    const float* __restrict__ bn, const float* __restrict__ wcat,
    unsigned short* __restrict__ Wh, unsigned short* __restrict__ Wl,
    float* __restrict__ sortedTheta, int* __restrict__ rankArr)
{
    int tid = threadIdx.x;
    int gtid = blockIdx.x * 256 + tid;
    for (int idx = gtid; idx < OUTC * INC; idx += 8 * 256) {
        int col = idx >> 8;     // W0 is [112][256] row-major
        int k   = idx & 255;
        float w = W0[idx] * wcat[col * 2 + 0];
        unsigned short hi = bf16_rne(w);
        float resid = w - bf16_to_f32(hi);
        unsigned short lo = bf16_rne(resid);
        int dst = (k >> 3) * (OUTC * 8) + col * 8 + (k & 7);
        Wh[dst] = hi;
        Wl[dst] = lo;
    }
    if (blockIdx.x == 0) {
        __shared__ float sth[128];
        float th = INFINITY;
        if (tid < 112) {
            float w = Wn[tid];
            th = (w != 0.0f) ? (-bn[tid] / w) : INFINITY;
        }
        if (tid < 128) sth[tid] = th;
        __syncthreads();
        if (tid < 128) {
            int rank = 0;
            for (int i = 0; i < 128; ++i) {
                float o = sth[i];
                rank += (o < th) || (o == th && i < tid);
            }
            sortedTheta[rank] = th;   // 128 entries; pads sort to top as +inf
            rankArr[tid] = rank;
        }
    }
}

// ---------------- Prepass 2: per-segment linear tables ----------------
__global__ __launch_bounds__(128) void prep2(
    const float* __restrict__ Wn, const float* __restrict__ bn,
    const float* __restrict__ Wc, const float* __restrict__ bc,
    const float* __restrict__ wcat, const float* __restrict__ bcat,
    const float* __restrict__ b0, const int* __restrict__ rankArr,
    float* __restrict__ Atab, float* __restrict__ Ctab)
{
    int s = blockIdx.x;      // 0..112
    int k = threadIdx.x;     // 0..127
    __shared__ float sw[112], sb[112];
    __shared__ int sr[112];
    if (k < 112) { sw[k] = Wn[k]; sb[k] = bn[k]; sr[k] = rankArr[k]; }
    __syncthreads();
    if (k >= OUTC) return;
    float a = 0.f, c = 0.f;
    const float* wcrow = Wc + k * OUTC;
    for (int j = 0; j < OUTC; ++j) {
        float w = sw[j];
        bool act = (w == 0.0f) ? (sb[j] > 0.0f)
                               : ((w > 0.0f) ? (sr[j] < s) : (sr[j] >= s));
        if (act) { float wc = wcrow[j]; a += wc * w; c += wc * sb[j]; }
    }
    float w1 = wcat[k * 2 + 1];
    Atab[s * OUTC + k] = w1 * a;
    Ctab[s * OUTC + k] = w1 * (c + bc[k]) + bcat[k] + wcat[k * 2 + 0] * b0[k];
}

// ---------------- Main kernel ----------------
// 1024 threads = 16 waves x 16 rows = 256 rows/block. Full W hi+lo (114688 B)
// is staged into LDS once with plain load/ds_write, one __syncthreads, then
// the K-loop (4 phases x 2 k-tiles) is BARRIER-FREE: W via lgkmcnt (compiler
// managed), x is the only vmcnt traffic and is freely prefetched by the
// scheduler. All layouts identical to the round-4 passing kernel.
__global__ __launch_bounds__(1024, 4) void NodePredictor_main(
    const float* __restrict__ x, const float* __restrict__ node_info,
    const f32x4* __restrict__ Wg,          // Wh(57344B) | Wl(57344B) contiguous
    const float* __restrict__ sTheta,
    const float* __restrict__ Atab, const float* __restrict__ Ctab,
    float* __restrict__ out)
{
    __shared__ __align__(16) short LW[57344];   // 114688 B: Wh | Wl
    __shared__ float sTh[128];

    const int tid  = threadIdx.x;
    const int lane = tid & 63;
    const int wv   = tid >> 6;           // 0..15
    const int l15  = lane & 15;
    const int kg   = lane >> 4;          // 0..3 k-group

    // ---- stage full W into LDS: 7168 x 16B chunks, 7 per thread ----
    {
        f32x4* dst = (f32x4*)LW;
        #pragma unroll
        for (int r = 0; r < 7; ++r) {
            int i = r * 1024 + tid;
            dst[i] = Wg[i];
        }
    }
    if (tid < 128) sTh[tid] = sTheta[tid];
    __syncthreads();

    const long row  = (long)blockIdx.x * 256 + wv * 16 + l15;
    const long rowc = row < NROWS ? row : (NROWS - 1);
    const float* xrow = x + rowc * (long)INC;

    // MFMA phase p (k-tiles 2p, 2p+1): g = 8p+kg and 8p+4+kg
    auto MM = [&](int p, const short8& ah0, const short8& al0,
                         const short8& ah1, const short8& al1, f32x4* acc) {
        #pragma unroll
        for (int ct = 0; ct < 7; ++ct) {
            int e = (ct * 16 + l15) * 8;
            const short* b0p = LW + (8 * p + kg) * 896 + e;
            const short* b1p = LW + (8 * p + 4 + kg) * 896 + e;
            short8 bh0 = *(const short8*)(b0p);
            short8 bl0 = *(const short8*)(b0p + 28672);
            short8 bh1 = *(const short8*)(b1p);
            short8 bl1 = *(const short8*)(b1p + 28672);
            acc[ct] = __builtin_amdgcn_mfma_f32_16x16x32_bf16(bh0, ah0, acc[ct], 0, 0, 0);
            acc[ct] = __builtin_amdgcn_mfma_f32_16x16x32_bf16(bl0, ah0, acc[ct], 0, 0, 0);
            acc[ct] = __builtin_amdgcn_mfma_f32_16x16x32_bf16(bh0, al0, acc[ct], 0, 0, 0);
            acc[ct] = __builtin_amdgcn_mfma_f32_16x16x32_bf16(bh1, ah1, acc[ct], 0, 0, 0);
            acc[ct] = __builtin_amdgcn_mfma_f32_16x16x32_bf16(bl1, ah1, acc[ct], 0, 0, 0);
            acc[ct] = __builtin_amdgcn_mfma_f32_16x16x32_bf16(bh1, al1, acc[ct], 0, 0, 0);
        }
    };

    #define LOADX(v0, v1, v2, v3, q) { \
        const float* p_ = xrow + (q) * 64 + kg * 8; \
        v0 = *(const f32x4*)(p_);      v1 = *(const f32x4*)(p_ + 4); \
        v2 = *(const f32x4*)(p_ + 32); v3 = *(const f32x4*)(p_ + 36); }

    f32x4 xa0, xa1, xa2, xa3, xb0, xb1, xb2, xb3;
    f32x4 acc[7];
    #pragma unroll
    for (int ct = 0; ct < 7; ++ct) acc[ct] = (f32x4){0.f, 0.f, 0.f, 0.f};

    LOADX(xa0, xa1, xa2, xa3, 0);      // k-tiles 0,1
    LOADX(xb0, xb1, xb2, xb3, 1);      // k-tiles 2,3

    short8 ah0, al0, ah1, al1;

    // phase 0: consume xa (kt 0,1), prefetch k-tiles 4,5
    conv8(xa0, xa1, ah0, al0); conv8(xa2, xa3, ah1, al1);
    LOADX(xa0, xa1, xa2, xa3, 2);
    MM(0, ah0, al0, ah1, al1, acc);

    // phase 1: consume xb (kt 2,3), prefetch k-tiles 6,7
    conv8(xb0, xb1, ah0, al0); conv8(xb2, xb3, ah1, al1);
    LOADX(xb0, xb1, xb2, xb3, 3);
    MM(1, ah0, al0, ah1, al1, acc);

    // phase 2: consume xa (kt 4,5)
    conv8(xa0, xa1, ah0, al0); conv8(xa2, xa3, ah1, al1);
    MM(2, ah0, al0, ah1, al1, acc);

    // phase 3: consume xb (kt 6,7)
    conv8(xb0, xb1, ah0, al0); conv8(xb2, xb3, ah1, al1);
    MM(3, ah0, al0, ah1, al1, acc);

    // ---- epilogue: out[row][col..col+3] = acc + A[seg]*t + C[seg] ----
    float t = node_info[rowc];
    int seg = 0;
    #pragma unroll
    for (int st = 64; st > 0; st >>= 1)
        if (sTh[seg + st - 1] < t) seg += st;   // #{theta < t}; pads are +inf

    if (row < NROWS) {
        const float* Ar = Atab + seg * OUTC;
        const float* Cr = Ctab + seg * OUTC;
        float* orow = out + row * (long)OUTC;
        #pragma unroll
        for (int ct = 0; ct < 7; ++ct) {
            int col = ct * 16 + kg * 4;
            f32x4 Av = *(const f32x4*)(Ar + col);
            f32x4 Cv = *(const f32x4*)(Cr + col);
            f32x4 v = acc[ct], o;
            #pragma unroll
            for (int i = 0; i < 4; ++i) o[i] = v[i] + Av[i] * t + Cv[i];
            __builtin_nontemporal_store(o, (f32x4*)(orow + col));
        }
    }
    #undef LOADX
}

extern "C" void kernel_launch(void* const* d_in, const int* in_sizes, int n_in,
                              void* d_out, int out_size, void* d_ws, size_t ws_size,
                              hipStream_t stream)
{
    const float* x    = (const float*)d_in[0];
    const float* ni   = (const float*)d_in[1];
    const float* W0   = (const float*)d_in[2];
    const float* b0   = (const float*)d_in[3];
    const float* Wn   = (const float*)d_in[4];
    const float* bn   = (const float*)d_in[5];
    const float* Wc   = (const float*)d_in[6];
    const float* bc   = (const float*)d_in[7];
    const float* wcat = (const float*)d_in[8];
    const float* bcat = (const float*)d_in[9];
    float* out = (float*)d_out;

    char* ws = (char*)d_ws;
    unsigned short* Wh   = (unsigned short*)(ws);              // 57344 B
    unsigned short* Wl   = (unsigned short*)(ws + 57344);      // 57344 B (contiguous with Wh)
    float* sTheta        = (float*)(ws + 114688);              // 512 B
    int* rankArr         = (int*)(ws + 115200);                // 512 B
    float* Atab          = (float*)(ws + 115712);              // 50624 B
    float* Ctab          = (float*)(ws + 166336);              // 50624 B

    prep1<<<8, 256, 0, stream>>>(W0, Wn, bn, wcat, Wh, Wl, sTheta, rankArr);
    prep2<<<113, 128, 0, stream>>>(Wn, bn, Wc, bc, wcat, bcat, b0, rankArr, Atab, Ctab);

    const int blocks = (NROWS + 255) / 256;    // 1954
    NodePredictor_main<<<blocks, 1024, 0, stream>>>(
        x, ni, (const f32x4*)ws, sTheta, Atab, Ctab, out);
}